// Round 2
// baseline (364.265 us; speedup 1.0000x reference)
//
#include <hip/hip_runtime.h>
#include <hip/hip_bf16.h>

// 1-NN VQ: x -> Q[M=131072][C=128] fp32, codebook [K=256][C=128] fp32 -> int32 idx[M]
// argmin_k (c_sq[k] - 2*q.c_k)
//
// Lane = query. Query row held in VGPRs (128). Code rows are wave-uniform ->
// scalar loads (s_load_dwordx16) on the scalar pipe; inner loop is a pure
// v_fmac_f32 vgpr,sgpr,vgpr stream. Running argmin in registers (strict <
// keeps lowest k = np first-occurrence). LDS only holds csq[256] (1 KB),
// computed per-block in a prologue.

#define C 128
#define K 256

__global__ __launch_bounds__(256, 2) void knn_kernel(const float* __restrict__ x,
                                                     const float* __restrict__ cb,
                                                     int* __restrict__ out) {
    __shared__ float s_csq[K];

    const int tid = threadIdx.x;

    // ---- per-block csq precompute: thread t -> code t (K == blockDim) ----
    {
        const float4* row = (const float4*)(cb + (size_t)tid * C);
        float a0 = 0.f, a1 = 0.f, a2 = 0.f, a3 = 0.f;
#pragma unroll
        for (int j = 0; j < C / 4; ++j) {
            float4 v = row[j];
            a0 = fmaf(v.x, v.x, a0);
            a1 = fmaf(v.y, v.y, a1);
            a2 = fmaf(v.z, v.z, a2);
            a3 = fmaf(v.w, v.w, a3);
        }
        s_csq[tid] = (a0 + a1) + (a2 + a3);
    }
    __syncthreads();

    // ---- this lane's query row into registers ----
    const int lane = tid & 63;
    const int wave = tid >> 6;
    const size_t q = (size_t)blockIdx.x * 256 + (size_t)wave * 64 + lane;

    float qv[C];
    {
        const float4* qr = (const float4*)(x + q * C);
#pragma unroll
        for (int j = 0; j < C / 4; ++j) {
            float4 v = qr[j];
            qv[4 * j + 0] = v.x;
            qv[4 * j + 1] = v.y;
            qv[4 * j + 2] = v.z;
            qv[4 * j + 3] = v.w;
        }
    }

    // ---- main loop: all 256 codes, code row via scalar loads ----
    float best = 3.0e38f;
    int bidx = 0;
#pragma unroll 1
    for (int k = 0; k < K; ++k) {
        const float* crow = cb + k * C;   // wave-uniform address -> s_load
        float a0 = 0.f, a1 = 0.f, a2 = 0.f, a3 = 0.f;
#pragma unroll
        for (int c = 0; c < C; c += 4) {
            a0 = fmaf(crow[c + 0], qv[c + 0], a0);
            a1 = fmaf(crow[c + 1], qv[c + 1], a1);
            a2 = fmaf(crow[c + 2], qv[c + 2], a2);
            a3 = fmaf(crow[c + 3], qv[c + 3], a3);
        }
        float dot = (a0 + a1) + (a2 + a3);
        float score = fmaf(-2.0f, dot, s_csq[k]);  // same formula as ref path
        if (score < best) { best = score; bidx = k; }
    }

    out[q] = bidx;
}

extern "C" void kernel_launch(void* const* d_in, const int* in_sizes, int n_in,
                              void* d_out, int out_size, void* d_ws, size_t ws_size,
                              hipStream_t stream) {
    const float* x = (const float*)d_in[0];
    const float* cb = (const float*)d_in[1];
    int* out = (int*)d_out;

    const int M = in_sizes[0] / C;       // 131072
    dim3 grid(M / 256);                  // 512 blocks x 256 threads, lane = query
    knn_kernel<<<grid, 256, 0, stream>>>(x, cb, out);
}

// Round 3
// 339.414 us; speedup vs baseline: 1.0732x; 1.0732x over previous
//
#include <hip/hip_runtime.h>
#include <hip/hip_bf16.h>

// 1-NN VQ: Q[M=131072][C=128] fp32, codebook [K=256][C=128] fp32 -> int32 argmin idx.
// score = csq[k] - 2*dot(q,c_k); argmin with lowest-k tie-break (np first occurrence).
//
// Block = 256 thr = 4 waves, QB=64 queries. Wave w owns codes [w*64, w*64+64).
// Lane (qg=lane>>3, kg=lane&7): TQ=8 queries x TK=8 codes, 64 fp32 accumulators.
// Query tile in LDS, XOR-swizzled so the 8 concurrent broadcast reads hit 8
// distinct bank-quads (padding cannot fix q-stride==0 mod 32 while keeping
// 16B alignment; swizzle can). Codes read as global b128 (L1/L2-resident).
// Per c4-step per wave: 8 ds_read_b128 + 8 global b128 + 256 v_fmac -> VALU-bound.

#define C 128
#define K 256
#define QB 64

__device__ __forceinline__ unsigned fmap(float f) {
    unsigned u = __float_as_uint(f);
    return (u & 0x80000000u) ? ~u : (u | 0x80000000u);
}

__global__ __launch_bounds__(256, 3) void knn_kernel(const float* __restrict__ x,
                                                     const float* __restrict__ cb,
                                                     int* __restrict__ out) {
    __shared__ float sQ[QB * C];                  // 32 KB, swizzled
    __shared__ float s_csq[K];                    // 1 KB
    __shared__ unsigned long long sW[QB][4];      // 2 KB

    const int tid = threadIdx.x;
    const int wave = tid >> 6;
    const int lane = tid & 63;
    const int qg = lane >> 3;    // 0..7 -> query group
    const int kg = lane & 7;     // 0..7 -> code group

    // ---- csq[k] per block (thread t -> code t) ----
    {
        const float4* row = (const float4*)(cb + (size_t)tid * C);
        float a0 = 0.f, a1 = 0.f, a2 = 0.f, a3 = 0.f;
#pragma unroll
        for (int j = 0; j < C / 4; ++j) {
            float4 v = row[j];
            a0 = fmaf(v.x, v.x, a0);
            a1 = fmaf(v.y, v.y, a1);
            a2 = fmaf(v.z, v.z, a2);
            a3 = fmaf(v.w, v.w, a3);
        }
        s_csq[tid] = (a0 + a1) + (a2 + a3);
    }

    // ---- stage query tile, swizzled: (q, c4) block -> sQ[q*C + (c4 ^ ((q>>3)&7))*4] ----
    {
        const float4* xin = (const float4*)(x + (size_t)blockIdx.x * (QB * C));
#pragma unroll
        for (int i = 0; i < (QB * C / 4) / 256; ++i) {   // 8 iters
            int chunk = i * 256 + tid;                   // 0..2047
            int q = chunk >> 5;                          // 32 c4-blocks per row
            int c4 = chunk & 31;
            float4 v = xin[chunk];
            int sw = c4 ^ ((q >> 3) & 7);
            *(float4*)(sQ + q * C + sw * 4) = v;
        }
    }
    __syncthreads();

    // ---- main loop ----
    float acc[8][8];
#pragma unroll
    for (int i = 0; i < 8; ++i)
#pragma unroll
        for (int j = 0; j < 8; ++j) acc[i][j] = 0.0f;

    const int k0 = wave * 64 + kg * 8;
    const int q0 = qg * 8;

    for (int c4 = 0; c4 < C / 4; ++c4) {
        float4 code[8];
#pragma unroll
        for (int j = 0; j < 8; ++j)
            code[j] = *(const float4*)(cb + (size_t)(k0 + j) * C + c4 * 4);

        float4 qq[8];
        const int sw = (c4 ^ qg) * 4;
#pragma unroll
        for (int i = 0; i < 8; ++i)
            qq[i] = *(const float4*)(sQ + (q0 + i) * C + sw);

#pragma unroll
        for (int i = 0; i < 8; ++i)
#pragma unroll
            for (int j = 0; j < 8; ++j) {
                float a = acc[i][j];
                a = fmaf(qq[i].x, code[j].x, a);
                a = fmaf(qq[i].y, code[j].y, a);
                a = fmaf(qq[i].z, code[j].z, a);
                a = fmaf(qq[i].w, code[j].w, a);
                acc[i][j] = a;
            }
    }

    // ---- scores + argmin: local over 8 codes, shuffle over 8 kg lanes ----
    unsigned long long key[8];
#pragma unroll
    for (int i = 0; i < 8; ++i) {
        unsigned long long b = ~0ULL;
#pragma unroll
        for (int j = 0; j < 8; ++j) {
            float score = fmaf(-2.0f, acc[i][j], s_csq[k0 + j]);
            unsigned long long kk =
                ((unsigned long long)fmap(score) << 32) | (unsigned)(k0 + j);
            b = kk < b ? kk : b;
        }
        key[i] = b;
    }
#pragma unroll
    for (int i = 0; i < 8; ++i) {
        unsigned long long o;
        o = __shfl_xor(key[i], 1); key[i] = o < key[i] ? o : key[i];
        o = __shfl_xor(key[i], 2); key[i] = o < key[i] ? o : key[i];
        o = __shfl_xor(key[i], 4); key[i] = o < key[i] ? o : key[i];
    }
    if (kg == 0) {
#pragma unroll
        for (int i = 0; i < 8; ++i) sW[q0 + i][wave] = key[i];
    }
    __syncthreads();

    // ---- cross-wave combine + write ----
    if (tid < QB) {
        unsigned long long b = sW[tid][0];
        unsigned long long o;
        o = sW[tid][1]; b = o < b ? o : b;
        o = sW[tid][2]; b = o < b ? o : b;
        o = sW[tid][3]; b = o < b ? o : b;
        out[(size_t)blockIdx.x * QB + tid] = (int)(unsigned)(b & 0xFFFFFFFFull);
    }
}

extern "C" void kernel_launch(void* const* d_in, const int* in_sizes, int n_in,
                              void* d_out, int out_size, void* d_ws, size_t ws_size,
                              hipStream_t stream) {
    const float* x = (const float*)d_in[0];
    const float* cb = (const float*)d_in[1];
    int* out = (int*)d_out;

    const int M = in_sizes[0] / C;       // 131072
    dim3 grid(M / QB);                   // 2048 blocks
    knn_kernel<<<grid, 256, 0, stream>>>(x, cb, out);
}